// Round 7
// baseline (438.035 us; speedup 1.0000x reference)
//
#include <hip/hip_runtime.h>

#define NN 100000
#define NE 600000
#define ET (NE + NN)
#define D 128
#define NREL 16
#define SCANB 391   // 391*256 = 100096 >= NN (k_self0 grid)
#define MAXTILES 10954
#define WGRID 1088  // 17*16384/256

typedef short short8 __attribute__((ext_vector_type(8)));
typedef float f32x4 __attribute__((ext_vector_type(4)));

// meta layout (ints)
#define C0 0    // counts[17]
#define O0 20   // offsets[18]
#define CU0 40  // cursors[17]
#define T0 60   // tileoff[18]

// ws layout (bytes)
#define WT_OFF   0                 // 17*128*128 bf16 = 557056
#define META_OFF 557056            // 512
#define SCP_OFF  557568            // sCP: 700064 int2 = 5600512
#define XB_OFF   6158080           // xb: 100000*128 bf16 = 25600000
#define NEED_XB  (XB_OFF + (size_t)NN * D * 2)

__device__ __forceinline__ unsigned short f2bf(float f) {
  unsigned u = __builtin_bit_cast(unsigned, f);
  u += 0x7fffu + ((u >> 16) & 1u);   // RNE; inputs finite/normal
  return (unsigned short)(u >> 16);
}

// LDS-only barrier: no vmcnt drain (R3-R6-validated construct)
__device__ __forceinline__ void lds_barrier() {
  asm volatile("s_waitcnt lgkmcnt(0)" ::: "memory");
  __builtin_amdgcn_s_barrier();
}

// blockIdx < WGRID: wT[r][o][i] = sum_b coef[r,b]*bases[b][i][o]; slot16 = w_self.
// else: x fp32 -> xb bf16 (4 elems/thread).
__global__ __launch_bounds__(256) void k_prep(const float* __restrict__ bases,
    const float* __restrict__ coef, const float* __restrict__ w_self,
    unsigned short* __restrict__ wT, const float* __restrict__ x,
    unsigned short* __restrict__ xb)
{
  if (blockIdx.x < WGRID) {
    int idx = blockIdx.x * 256 + threadIdx.x;   // < 17*16384
    int r = idx >> 14;
    int t = idx & 16383;
    float v;
    if (r < 16) {
      int o = t >> 7, i = t & 127;
      float acc = 0.f;
      #pragma unroll
      for (int b = 0; b < 8; ++b)
        acc += coef[r * 8 + b] * bases[b * 16384 + i * 128 + o];
      v = acc;
    } else {
      v = w_self[t];
    }
    wT[idx] = f2bf(v);
  } else {
    int i = (blockIdx.x - WGRID) * 256 + threadIdx.x;
    if (i >= NN * D / 4) return;
    f32x4 f = __builtin_nontemporal_load((const f32x4*)(x + (size_t)i * 4));
    unsigned short s0 = f2bf(f[0]), s1 = f2bf(f[1]), s2 = f2bf(f[2]), s3 = f2bf(f[3]);
    unsigned long long pk = (unsigned long long)s0 | ((unsigned long long)s1 << 16)
                          | ((unsigned long long)s2 << 32) | ((unsigned long long)s3 << 48);
    *(unsigned long long*)(xb + (size_t)i * 4) = pk;
  }
}

// rel histogram only (no dst machinery in atomic mode)
__global__ __launch_bounds__(256) void k_hist(const int* __restrict__ et,
    int* __restrict__ meta)
{
  __shared__ int h[16];
  int tid = threadIdx.x;
  if (tid < 16) h[tid] = 0;
  __syncthreads();
  for (int e = blockIdx.x * 256 + tid; e < NE; e += gridDim.x * 256)
    atomicAdd(&h[et[e]], 1);
  __syncthreads();
  if (tid < 16) atomicAdd(&meta[C0 + tid], h[tid]);
}

// tiny: 17-bin offsets/cursors/tile-offsets
__global__ __launch_bounds__(64) void k_meta(int* __restrict__ meta)
{
  if (threadIdx.x == 0) {
    meta[C0 + 16] = NN;
    int off = 0, toff = 0;
    for (int r = 0; r <= 16; ++r) {
      meta[O0 + r] = off;
      meta[CU0 + r] = off;
      meta[T0 + r] = toff;
      int c = meta[C0 + r];
      off += c;
      toff += (c + 63) >> 6;
    }
    meta[O0 + 17] = off;
    meta[T0 + 17] = toff;
  }
}

// self entries: sCP = (src=n, row=n) at slot O0[16]+n (O0[16] == NE always)
__global__ __launch_bounds__(256) void k_self0(int2* __restrict__ sCP)
{
  int n = blockIdx.x * 256 + threadIdx.x;
  if (n < NN) sCP[NE + n] = make_int2(n, n);
}

// bin edges by relation: sCP[pos] = (src, dstRow). No cursor atomics on dst.
__global__ __launch_bounds__(256) void k_scatter(const int* __restrict__ ei, const int* __restrict__ et,
    int* __restrict__ meta, int2* __restrict__ sCP)
{
  __shared__ int h[16], base[16], lh[16];
  int tid = threadIdx.x;
  int start = blockIdx.x * 4096;
  int end = min(NE, start + 4096);
  if (tid < 16) { h[tid] = 0; lh[tid] = 0; }
  __syncthreads();
  for (int e = start + tid; e < end; e += 256)
    atomicAdd(&h[et[e]], 1);
  __syncthreads();
  if (tid < 16) base[tid] = atomicAdd(&meta[CU0 + tid], h[tid]);
  __syncthreads();
  for (int e = start + tid; e < end; e += 256) {
    int r = et[e];
    int pos = base[r] + atomicAdd(&lh[r], 1);
    sCP[pos] = make_int2(ei[NE + e], ei[e]);
  }
}

// ONE tile per block: gather -> As -> barrier -> MFMA -> fp32 atomic scatter to out.
// No msg buffer, no Es transpose, one barrier. Atomics execute at the memory-side
// coherence point; out (51MB) is LLC-resident so the RMW stream stays on-die.
__global__ __launch_bounds__(256) void k_gemm(const float* __restrict__ xf,
    const unsigned short* __restrict__ xb,
    const unsigned short* __restrict__ wT, const int* __restrict__ meta,
    const int2* __restrict__ sCP, float* __restrict__ out, int xbf)
{
  __shared__ short As[64 * 17 * 8];   // 17.4KB staging
  __shared__ int Rows[64];
  __shared__ int Ms[80];

  int tid = threadIdx.x;
  if (tid < 80) Ms[tid] = meta[tid];
  __syncthreads();
  int ntiles = Ms[T0 + 17];
  int b = blockIdx.x;
  if (b >= ntiles) return;

  int lane = tid & 63, wave = tid >> 6;
  int q = lane >> 4, l15 = lane & 15;
  int m = tid >> 2, ug = tid & 3;

  int r = 0;
  while (r < 16 && Ms[T0 + r + 1] <= b) ++r;
  int boff = Ms[O0 + r];
  int e0 = boff + (b - Ms[T0 + r]) * 64;
  int nr = min(64, boff + Ms[C0 + r] - e0);

  bool valid = m < nr;
  int e = valid ? (e0 + m) : e0;
  int2 cp = sCP[e];
  if (ug == 0) Rows[m] = valid ? cp.y : 0;

  // ---- stage gather row m into As ----
  if (xbf) {
    const unsigned short* xr = xb + (size_t)cp.x * 128;
    #pragma unroll
    for (int s = 0; s < 4; ++s) {
      int u = ug * 4 + s;
      short8 pk = (short8)(short)0;
      if (valid) pk = *(const short8*)(xr + u * 8);
      *(short8*)&As[(m * 17 + u) * 8] = pk;
    }
  } else {
    const float* xr = xf + (size_t)cp.x * 128;
    #pragma unroll
    for (int s = 0; s < 4; ++s) {
      int u = ug * 4 + s;
      float4 f0 = make_float4(0.f, 0.f, 0.f, 0.f), f1 = f0;
      if (valid) {
        f0 = *(const float4*)(xr + u * 8);
        f1 = *(const float4*)(xr + u * 8 + 4);
      }
      short8 pk;
      pk[0] = (short)f2bf(f0.x); pk[1] = (short)f2bf(f0.y);
      pk[2] = (short)f2bf(f0.z); pk[3] = (short)f2bf(f0.w);
      pk[4] = (short)f2bf(f1.x); pk[5] = (short)f2bf(f1.y);
      pk[6] = (short)f2bf(f1.z); pk[7] = (short)f2bf(f1.w);
      *(short8*)&As[(m * 17 + u) * 8] = pk;
    }
  }

  // ---- B frags (pre-barrier; overlaps other waves' staging) ----
  short8 bfr[2][4];
  {
    const unsigned short* wr = wT + r * 16384;
    #pragma unroll
    for (int ns = 0; ns < 2; ++ns)
      #pragma unroll
      for (int kk = 0; kk < 4; ++kk)
        bfr[ns][kk] = *(const short8*)(wr + (wave * 32 + ns * 16 + l15) * 128 + kk * 32 + q * 8);
  }

  lds_barrier();   // As/Rows visible

  // ---- MFMA ----
  f32x4 acc[4][2];
  #pragma unroll
  for (int ms = 0; ms < 4; ++ms)
    #pragma unroll
    for (int ns = 0; ns < 2; ++ns)
      acc[ms][ns] = (f32x4){0.f, 0.f, 0.f, 0.f};
  #pragma unroll
  for (int kk = 0; kk < 4; ++kk) {
    short8 af[4];
    #pragma unroll
    for (int ms = 0; ms < 4; ++ms)
      af[ms] = *(const short8*)&As[((ms * 16 + l15) * 17 + kk * 4 + q) * 8];
    #pragma unroll
    for (int ms = 0; ms < 4; ++ms)
      #pragma unroll
      for (int ns = 0; ns < 2; ++ns)
        acc[ms][ns] = __builtin_amdgcn_mfma_f32_16x16x32_bf16(af[ms], bfr[ns][kk], acc[ms][ns], 0, 0, 0);
  }

  // ---- epilogue: direct fp32 atomic scatter (16-lane groups write 64B segments) ----
  #pragma unroll
  for (int ms = 0; ms < 4; ++ms)
    #pragma unroll
    for (int reg = 0; reg < 4; ++reg) {
      int erow = ms * 16 + q * 4 + reg;
      if (erow < nr) {
        float* op = out + (size_t)Rows[erow] * 128 + wave * 32 + l15;
        unsafeAtomicAdd(op, acc[ms][0][reg]);
        unsafeAtomicAdd(op + 16, acc[ms][1][reg]);
      }
    }
}

extern "C" void kernel_launch(void* const* d_in, const int* in_sizes, int n_in,
                              void* d_out, int out_size, void* d_ws, size_t ws_size,
                              hipStream_t stream)
{
  const float* x      = (const float*)d_in[0];
  const int*   ei     = (const int*)d_in[1];
  const int*   et     = (const int*)d_in[2];
  const float* bases  = (const float*)d_in[3];
  const float* coef   = (const float*)d_in[4];
  const float* w_self = (const float*)d_in[5];
  float* out = (float*)d_out;
  char* ws = (char*)d_ws;
  unsigned short* wT = (unsigned short*)(ws + WT_OFF);
  int* meta      = (int*)(ws + META_OFF);
  int2* sCP      = (int2*)(ws + SCP_OFF);
  unsigned short* xb = (unsigned short*)(ws + XB_OFF);

  const int xbf = (ws_size >= NEED_XB) ? 1 : 0;

  hipMemsetAsync(ws + META_OFF, 0, 512, stream);
  hipMemsetAsync(d_out, 0, (size_t)NN * D * 4, stream);
  k_prep<<<xbf ? (WGRID + 12500) : WGRID, 256, 0, stream>>>(bases, coef, w_self, wT, x, xb);
  k_hist<<<256, 256, 0, stream>>>(et, meta);
  k_meta<<<1, 64, 0, stream>>>(meta);
  k_self0<<<SCANB, 256, 0, stream>>>(sCP);
  k_scatter<<<(NE + 4095) / 4096, 256, 0, stream>>>(ei, et, meta, sCP);
  k_gemm<<<MAXTILES, 256, 0, stream>>>(x, xb, wT, meta, sCP, out, xbf);
}

// Round 9
// 329.666 us; speedup vs baseline: 1.3287x; 1.3287x over previous
//
#include <hip/hip_runtime.h>

#define NN 100000
#define NE 600000
#define ET (NE + NN)
#define D 128
#define NREL 16
#define SCANB 391   // 391*256 = 100096 >= NN
#define TPB 4
#define MAXTILES 10954
#define GEMMG ((MAXTILES + TPB - 1) / TPB)
#define WGRID 1088  // 17*16384/256

typedef short short8 __attribute__((ext_vector_type(8)));
typedef float f32x4 __attribute__((ext_vector_type(4)));
typedef unsigned int u32x4 __attribute__((ext_vector_type(4)));

// meta layout (ints)
#define C0 0    // counts[17]
#define O0 20   // offsets[18]
#define CU0 40  // cursors[17]
#define T0 60   // tileoff[18]

// ws layout (bytes)
#define WT_OFF   0                 // 17*128*128 bf16 = 557056
#define META_OFF 557056            // 512
#define DH_OFF   557568            // dstHist: 100000 ints
#define DO_OFF   957568            // dstOff: 100001 ints (+pad)
#define DC_OFF   1357576           // dstCursor: 100000 ints
#define BS_OFF   1757576           // blockSums: 391 ints (+pad)
#define SSRC_OFF 1759576           // sSrc: ET ints = 2800000
#define IDX_OFF  4559576           // idx: ET ints  = 2800000
#define SDST_OFF 7359576           // sDst (fallback only): ET ints
#define XB_OFF   10159576          // xb: 100000*128 bf16 = 25600000
#define MSG_OFF  35759576          // msg: ET*256 B
#define NEED_XB  (XB_OFF + (size_t)NN * D * 2)
#define NEED_MSG (MSG_OFF + (size_t)ET * 128 * 2)

__device__ __forceinline__ unsigned short f2bf(float f) {
  unsigned u = __builtin_bit_cast(unsigned, f);
  u += 0x7fffu + ((u >> 16) & 1u);   // RNE; inputs finite/normal
  return (unsigned short)(u >> 16);
}

// merged: [0,WGRID) wT basis-combine; [WGRID,WGRID+12500) x->xb; last 256: histograms
__global__ __launch_bounds__(256) void k_ph(const float* __restrict__ bases,
    const float* __restrict__ coef, const float* __restrict__ w_self,
    unsigned short* __restrict__ wT, const float* __restrict__ x,
    unsigned short* __restrict__ xb, const int* __restrict__ ei,
    const int* __restrict__ et, int* __restrict__ meta, int* __restrict__ dstHist,
    int xbf, int doMsg)
{
  int bx = blockIdx.x;
  int tid = threadIdx.x;
  if (bx < WGRID) {
    int idx = bx * 256 + tid;   // < 17*16384
    int r = idx >> 14;
    int t = idx & 16383;
    float v;
    if (r < 16) {
      int o = t >> 7, i = t & 127;
      float acc = 0.f;
      #pragma unroll
      for (int b = 0; b < 8; ++b)
        acc += coef[r * 8 + b] * bases[b * 16384 + i * 128 + o];
      v = acc;
    } else {
      v = w_self[t];
    }
    wT[idx] = f2bf(v);
    return;
  }
  int hb0 = WGRID + (xbf ? 12500 : 0);
  if (bx < hb0) {
    int i = (bx - WGRID) * 256 + tid;
    if (i >= NN * D / 4) return;
    f32x4 f = __builtin_nontemporal_load((const f32x4*)(x + (size_t)i * 4));
    unsigned short s0 = f2bf(f[0]), s1 = f2bf(f[1]), s2 = f2bf(f[2]), s3 = f2bf(f[3]);
    unsigned long long pk = (unsigned long long)s0 | ((unsigned long long)s1 << 16)
                          | ((unsigned long long)s2 << 32) | ((unsigned long long)s3 << 48);
    *(unsigned long long*)(xb + (size_t)i * 4) = pk;
    return;
  }
  // histogram blocks (256 of them)
  __shared__ int h[16];
  int hb = bx - hb0;
  if (tid < 16) h[tid] = 0;
  __syncthreads();
  for (int e = hb * 256 + tid; e < NE; e += 256 * 256) {
    atomicAdd(&h[et[e]], 1);
    if (doMsg) atomicAdd(&dstHist[ei[e]], 1);
  }
  __syncthreads();
  if (tid < 16) atomicAdd(&meta[C0 + tid], h[tid]);
}

__global__ __launch_bounds__(256) void k_scan1(const int* __restrict__ dstHist,
    int* __restrict__ dstOff, int* __restrict__ blockSums)
{
  __shared__ int sh[256];
  int tid = threadIdx.x;
  int d = blockIdx.x * 256 + tid;
  int v = (d < NN) ? (dstHist[d] + 1) : 0;   // +1: virtual self edge
  sh[tid] = v;
  __syncthreads();
  #pragma unroll
  for (int ofs = 1; ofs < 256; ofs <<= 1) {
    int t = (tid >= ofs) ? sh[tid - ofs] : 0;
    __syncthreads();
    sh[tid] += t;
    __syncthreads();
  }
  if (d < NN) dstOff[d] = sh[tid] - v;
  if (tid == 255) blockSums[blockIdx.x] = sh[tid];
}

// parallel Hillis-Steele over 512 (padded) + serial 17-bin meta on tid0
__global__ __launch_bounds__(512) void k_scan2(int* __restrict__ blockSums, int* __restrict__ meta)
{
  __shared__ int sh[512];
  int tid = threadIdx.x;
  int v = (tid < SCANB) ? blockSums[tid] : 0;
  sh[tid] = v;
  __syncthreads();
  #pragma unroll
  for (int ofs = 1; ofs < 512; ofs <<= 1) {
    int t = (tid >= ofs) ? sh[tid - ofs] : 0;
    __syncthreads();
    sh[tid] += t;
    __syncthreads();
  }
  if (tid == 0) {
    meta[C0 + 16] = NN;
    int off = 0, toff = 0;
    for (int r = 0; r <= 16; ++r) {
      meta[O0 + r] = off;
      meta[CU0 + r] = off;
      meta[T0 + r] = toff;
      int c = meta[C0 + r];
      off += c;
      toff += (c + 63) >> 6;
    }
    meta[O0 + 17] = off;
    meta[T0 + 17] = toff;
  }
  if (tid < SCANB) blockSums[tid] = sh[tid] - v;   // exclusive prefix
}

// finalize dstOff; init cursor past self slot; self edges: msg row NE+d, idx at dstOff[d]
__global__ __launch_bounds__(256) void k_scan3(int* __restrict__ dstOff,
    const int* __restrict__ blockSums, int* __restrict__ dstCursor,
    int* __restrict__ sSrc, int* __restrict__ idx)
{
  int tid = threadIdx.x;
  int d = blockIdx.x * 256 + tid;
  int base = blockSums[blockIdx.x];
  if (d < NN) {
    int o = dstOff[d] + base;
    dstOff[d] = o;
    dstCursor[d] = o + 1;
    idx[o] = NE + d;
    sSrc[NE + d] = d;
  }
  if (d == NN) dstOff[NN] = ET;
}

// fallback meta (no dst machinery)
__global__ __launch_bounds__(64) void k_meta(int* __restrict__ meta)
{
  if (threadIdx.x == 0) {
    meta[C0 + 16] = NN;
    int off = 0, toff = 0;
    for (int r = 0; r <= 16; ++r) {
      meta[O0 + r] = off;
      meta[CU0 + r] = off;
      meta[T0 + r] = toff;
      int c = meta[C0 + r];
      off += c;
      toff += (c + 63) >> 6;
    }
    meta[O0 + 17] = off;
    meta[T0 + 17] = toff;
  }
}

__global__ __launch_bounds__(256) void k_selfF(int* __restrict__ sSrc, int* __restrict__ sDst)
{
  int n = blockIdx.x * 256 + threadIdx.x;
  if (n < NN) { sSrc[NE + n] = n; sDst[NE + n] = n; }
}

// bin edges by rel (bin order = msg row order). doMsg: inverted index idx[dstSlot]=pos.
__global__ __launch_bounds__(256) void k_scatter(const int* __restrict__ ei, const int* __restrict__ et,
    int* __restrict__ meta, int* __restrict__ sSrc, int* __restrict__ sDst,
    int* __restrict__ dstCursor, int* __restrict__ idx, int doMsg)
{
  __shared__ int h[16], base[16], lh[16];
  int tid = threadIdx.x;
  int start = blockIdx.x * 4096;
  int end = min(NE, start + 4096);
  if (tid < 16) { h[tid] = 0; lh[tid] = 0; }
  __syncthreads();
  for (int e = start + tid; e < end; e += 256)
    atomicAdd(&h[et[e]], 1);
  __syncthreads();
  if (tid < 16) base[tid] = atomicAdd(&meta[CU0 + tid], h[tid]);
  __syncthreads();
  for (int e = start + tid; e < end; e += 256) {
    int r = et[e];
    int row = ei[e];
    int pos = base[r] + atomicAdd(&lh[r], 1);
    sSrc[pos] = ei[NE + e];
    if (doMsg) idx[atomicAdd(&dstCursor[row], 1)] = pos;
    else sDst[pos] = row;
  }
}

// TPB tiles/block, full __syncthreads (R2/R4-validated sync structure; raw-s_barrier
// lds_barrier removed — IntrNoMem barrier let compiler hoist ds_reads above it = race).
// KEY: msg written in BIN order (pos=e0+row) -> each tile streams one contiguous
// 16KB block; dst-order scatter moved to k_reduce's read side via idx.
__global__ __launch_bounds__(256) void k_gemm(const float* __restrict__ xf,
    const unsigned short* __restrict__ xb,
    const unsigned short* __restrict__ wT, const int* __restrict__ meta,
    const int* __restrict__ sSrc, const int* __restrict__ sDst,
    unsigned short* __restrict__ msg, float* __restrict__ out,
    int xbf, int msgmode)
{
  __shared__ short As[64 * 17 * 8];
  __shared__ short Es[64 * 136];
  __shared__ int Rows[64];
  __shared__ int Ms[80];

  int tid = threadIdx.x;
  if (tid < 80) Ms[tid] = meta[tid];
  __syncthreads();
  int ntiles = Ms[T0 + 17];
  int b0 = blockIdx.x * TPB;
  if (b0 >= ntiles) return;

  int lane = tid & 63, wave = tid >> 6;
  int q = lane >> 4, l15 = lane & 15;
  int m = tid >> 2, ug = tid & 3;

  int rprev = -1;
  short8 bfr[2][4];

  if (xbf && msgmode) {
    for (int ti = 0; ti < TPB; ++ti) {
      int b = b0 + ti;
      if (b >= ntiles) break;
      int r = 0;
      while (r < 16 && Ms[T0 + r + 1] <= b) ++r;
      int boff = Ms[O0 + r];
      int e0 = boff + (b - Ms[T0 + r]) * 64;
      int nr = min(64, boff + Ms[C0 + r] - e0);

      bool valid = m < nr;
      int src = sSrc[valid ? (e0 + m) : e0];
      const unsigned short* xr = xb + (size_t)src * 128;
      #pragma unroll
      for (int s = 0; s < 4; ++s) {
        int u = ug * 4 + s;
        short8 pk = (short8)(short)0;
        if (valid) pk = *(const short8*)(xr + u * 8);
        *(short8*)&As[(m * 17 + u) * 8] = pk;
      }
      __syncthreads();   // As visible

      if (r != rprev) {
        const unsigned short* wr = wT + r * 16384;
        #pragma unroll
        for (int ns = 0; ns < 2; ++ns)
          #pragma unroll
          for (int kk = 0; kk < 4; ++kk)
            bfr[ns][kk] = *(const short8*)(wr + (wave * 32 + ns * 16 + l15) * 128 + kk * 32 + q * 8);
        rprev = r;
      }

      f32x4 acc[4][2];
      #pragma unroll
      for (int ms = 0; ms < 4; ++ms)
        #pragma unroll
        for (int ns = 0; ns < 2; ++ns)
          acc[ms][ns] = (f32x4){0.f, 0.f, 0.f, 0.f};
      #pragma unroll
      for (int kk = 0; kk < 4; ++kk) {
        short8 af[4];
        #pragma unroll
        for (int ms = 0; ms < 4; ++ms)
          af[ms] = *(const short8*)&As[((ms * 16 + l15) * 17 + kk * 4 + q) * 8];
        #pragma unroll
        for (int ms = 0; ms < 4; ++ms)
          #pragma unroll
          for (int ns = 0; ns < 2; ++ns)
            acc[ms][ns] = __builtin_amdgcn_mfma_f32_16x16x32_bf16(af[ms], bfr[ns][kk], acc[ms][ns], 0, 0, 0);
      }

      __syncthreads();   // As reads drained before Es reuse of LDS phase
      #pragma unroll
      for (int ms = 0; ms < 4; ++ms)
        #pragma unroll
        for (int ns = 0; ns < 2; ++ns)
          #pragma unroll
          for (int reg = 0; reg < 4; ++reg)
            Es[(ms * 16 + q * 4 + reg) * 136 + wave * 32 + ns * 16 + l15] =
                (short)f2bf(acc[ms][ns][reg]);
      __syncthreads();   // Es visible

      // SEQUENTIAL msg stores: tile = one contiguous 16KB stream
      #pragma unroll
      for (int i = 0; i < 4; ++i) {
        int row = wave * 16 + i * 4 + q;
        short8 v = *(const short8*)&Es[row * 136 + l15 * 8];
        if (row < nr)
          *(short8*)(msg + (size_t)(e0 + row) * 128 + l15 * 8) = v;
      }
      __syncthreads();   // Es reads drained before next tile's writes
    }
    return;
  }

  // ---------------- generic fallback (atomic out; correctness path) ----------------
  for (int ti = 0; ti < TPB; ++ti) {
    int b = b0 + ti;
    if (b >= ntiles) break;
    int r = 0;
    while (r < 16 && Ms[T0 + r + 1] <= b) ++r;
    int boff = Ms[O0 + r];
    int e0 = boff + (b - Ms[T0 + r]) * 64;
    int nrows = min(64, boff + Ms[C0 + r] - e0);

    bool valid = m < nrows;
    int e = valid ? (e0 + m) : e0;
    int src = sSrc[e];
    if (ug == 0) Rows[m] = valid ? sDst[e] : 0;

    if (xbf) {
      const unsigned short* xr = xb + (size_t)src * 128;
      #pragma unroll
      for (int s = 0; s < 4; ++s) {
        int u = ug * 4 + s;
        short8 pk = (short8)(short)0;
        if (valid) pk = *(const short8*)(xr + u * 8);
        *(short8*)&As[(m * 17 + u) * 8] = pk;
      }
    } else {
      const float* xr = xf + (size_t)src * 128;
      #pragma unroll
      for (int s = 0; s < 4; ++s) {
        int u = ug * 4 + s;
        float4 f0 = make_float4(0.f, 0.f, 0.f, 0.f), f1 = f0;
        if (valid) {
          f0 = *(const float4*)(xr + u * 8);
          f1 = *(const float4*)(xr + u * 8 + 4);
        }
        short8 pk;
        pk[0] = (short)f2bf(f0.x); pk[1] = (short)f2bf(f0.y);
        pk[2] = (short)f2bf(f0.z); pk[3] = (short)f2bf(f0.w);
        pk[4] = (short)f2bf(f1.x); pk[5] = (short)f2bf(f1.y);
        pk[6] = (short)f2bf(f1.z); pk[7] = (short)f2bf(f1.w);
        *(short8*)&As[(m * 17 + u) * 8] = pk;
      }
    }
    __syncthreads();

    if (r != rprev) {
      const unsigned short* wr = wT + r * 16384;
      #pragma unroll
      for (int ns = 0; ns < 2; ++ns)
        #pragma unroll
        for (int kk = 0; kk < 4; ++kk)
          bfr[ns][kk] = *(const short8*)(wr + (wave * 32 + ns * 16 + l15) * 128 + kk * 32 + q * 8);
      rprev = r;
    }

    f32x4 acc[4][2];
    #pragma unroll
    for (int ms = 0; ms < 4; ++ms)
      #pragma unroll
      for (int ns = 0; ns < 2; ++ns)
        acc[ms][ns] = (f32x4){0.f, 0.f, 0.f, 0.f};
    #pragma unroll
    for (int kk = 0; kk < 4; ++kk) {
      short8 af[4];
      #pragma unroll
      for (int ms = 0; ms < 4; ++ms)
        af[ms] = *(const short8*)&As[((ms * 16 + l15) * 17 + kk * 4 + q) * 8];
      #pragma unroll
      for (int ms = 0; ms < 4; ++ms)
        #pragma unroll
        for (int ns = 0; ns < 2; ++ns)
          acc[ms][ns] = __builtin_amdgcn_mfma_f32_16x16x32_bf16(af[ms], bfr[ns][kk], acc[ms][ns], 0, 0, 0);
    }

    __syncthreads();
    #pragma unroll
    for (int ms = 0; ms < 4; ++ms)
      #pragma unroll
      for (int reg = 0; reg < 4; ++reg) {
        int mrow = ms * 16 + q * 4 + reg;
        if (mrow < nrows) {
          float* op = out + (size_t)Rows[mrow] * 128 + wave * 32 + l15;
          unsafeAtomicAdd(op, acc[ms][0][reg]);
          unsafeAtomicAdd(op + 16, acc[ms][1][reg]);
        }
      }
    __syncthreads();
  }
}

// one 16-lane group per dst: idx-indirect gather of msg rows, fp32 accumulate, one store
__global__ __launch_bounds__(256) void k_reduce(const unsigned short* __restrict__ msg,
    const int* __restrict__ dstOff, const int* __restrict__ idx,
    float* __restrict__ out)
{
  int d = blockIdx.x * 16 + (threadIdx.x >> 4);
  if (d >= NN) return;
  int sl = threadIdx.x & 15;
  int s = dstOff[d], e = dstOff[d + 1];
  const unsigned short* base = msg + (size_t)sl * 8;
  float a[8], bacc[8];
  #pragma unroll
  for (int i = 0; i < 8; ++i) { a[i] = 0.f; bacc[i] = 0.f; }
  int j = s;
  for (; j + 1 < e; j += 2) {
    size_t p0 = (size_t)idx[j] * 128;
    size_t p1 = (size_t)idx[j + 1] * 128;
    u32x4 v0 = *(const u32x4*)(base + p0);
    u32x4 v1 = *(const u32x4*)(base + p1);
    #pragma unroll
    for (int c = 0; c < 4; ++c) {
      a[2 * c]     += __builtin_bit_cast(float, v0[c] << 16);
      a[2 * c + 1] += __builtin_bit_cast(float, v0[c] & 0xffff0000u);
      bacc[2 * c]     += __builtin_bit_cast(float, v1[c] << 16);
      bacc[2 * c + 1] += __builtin_bit_cast(float, v1[c] & 0xffff0000u);
    }
  }
  if (j < e) {
    u32x4 v0 = *(const u32x4*)(base + (size_t)idx[j] * 128);
    #pragma unroll
    for (int c = 0; c < 4; ++c) {
      a[2 * c]     += __builtin_bit_cast(float, v0[c] << 16);
      a[2 * c + 1] += __builtin_bit_cast(float, v0[c] & 0xffff0000u);
    }
  }
  f32x4 w0, w1;
  w0[0] = a[0] + bacc[0]; w0[1] = a[1] + bacc[1]; w0[2] = a[2] + bacc[2]; w0[3] = a[3] + bacc[3];
  w1[0] = a[4] + bacc[4]; w1[1] = a[5] + bacc[5]; w1[2] = a[6] + bacc[6]; w1[3] = a[7] + bacc[7];
  float* op = out + (size_t)d * 128 + sl * 8;
  __builtin_nontemporal_store(w0, (f32x4*)op);
  __builtin_nontemporal_store(w1, (f32x4*)(op + 4));
}

extern "C" void kernel_launch(void* const* d_in, const int* in_sizes, int n_in,
                              void* d_out, int out_size, void* d_ws, size_t ws_size,
                              hipStream_t stream)
{
  const float* x      = (const float*)d_in[0];
  const int*   ei     = (const int*)d_in[1];
  const int*   et     = (const int*)d_in[2];
  const float* bases  = (const float*)d_in[3];
  const float* coef   = (const float*)d_in[4];
  const float* w_self = (const float*)d_in[5];
  float* out = (float*)d_out;
  char* ws = (char*)d_ws;
  unsigned short* wT = (unsigned short*)(ws + WT_OFF);
  int* meta      = (int*)(ws + META_OFF);
  int* dstHist   = (int*)(ws + DH_OFF);
  int* dstOff    = (int*)(ws + DO_OFF);
  int* dstCursor = (int*)(ws + DC_OFF);
  int* blockSums = (int*)(ws + BS_OFF);
  int* sSrc      = (int*)(ws + SSRC_OFF);
  int* idx       = (int*)(ws + IDX_OFF);
  int* sDst      = (int*)(ws + SDST_OFF);
  unsigned short* xb = (unsigned short*)(ws + XB_OFF);
  unsigned short* msg = (unsigned short*)(ws + MSG_OFF);

  const int msgmode = (ws_size >= NEED_MSG) ? 1 : 0;
  const int xbf = (msgmode || ws_size >= NEED_XB) ? 1 : 0;

  hipMemsetAsync(ws + META_OFF, 0, 512 + 400000, stream);  // meta + dstHist
  k_ph<<<WGRID + (xbf ? 12500 : 0) + 256, 256, 0, stream>>>(
      bases, coef, w_self, wT, x, xb, ei, et, meta, dstHist, xbf, msgmode);
  if (msgmode) {
    k_scan1<<<SCANB, 256, 0, stream>>>(dstHist, dstOff, blockSums);
    k_scan2<<<1, 512, 0, stream>>>(blockSums, meta);
    k_scan3<<<SCANB, 256, 0, stream>>>(dstOff, blockSums, dstCursor, sSrc, idx);
  } else {
    k_meta<<<1, 64, 0, stream>>>(meta);
    k_selfF<<<SCANB, 256, 0, stream>>>(sSrc, sDst);
    hipMemsetAsync(d_out, 0, (size_t)NN * D * 4, stream);
  }
  k_scatter<<<(NE + 4095) / 4096, 256, 0, stream>>>(ei, et, meta, sSrc, sDst, dstCursor, idx, msgmode);
  k_gemm<<<GEMMG, 256, 0, stream>>>(x, xb, wT, meta, sSrc, sDst, msg, out, xbf, msgmode);
  if (msgmode)
    k_reduce<<<(NN + 15) / 16, 256, 0, stream>>>(msg, dstOff, idx, out);
}